// Round 5
// baseline (101.774 us; speedup 1.0000x reference)
//
#include <hip/hip_runtime.h>

// SuperPointMatchesGenerator: B=8, N0=N1=2048 mutual-NN under homography.
// d_out is FLOAT32 (reference outputs are int32/int32/float32 -> "else float*"
// per harness contract; rounds 1-4 failed by writing bf16 into an f32 buffer).
// Layout (f32, concat): gt_matches0[8,2048] | gt_matches1[8,2048] | min_dist0[8,2048]
//
// K1 (4096 blocks): blocks 0..2047    -> row argmin over kpts1  (gt0 packed u16 -> ws,
//                                        min_dist f32 -> chunk 2)
//                   blocks 2048..4095 -> col argmin over kpts0' (gt1 u16 -> ws)
// K2 (64 blocks):   race-free GATHER finalize, writes chunks 0 and 1 exactly once:
//     out1[j] = (i*=gt1[j]; gt0raw[i*]==j && !far[i*]) ? i* : -1
//   (validity forces injectivity => identical to the reference scatter-with-drop)
//
// FP exactness vs numpy-f32 (no FMA contraction, explicit __f*_rn):
//   p_i = (H[i0]*x + H[i1]*y) + H[i2];  X = p0/(p2+1e-8);  a2 = X*X + Y*Y;
//   d2  = (a2 + b2) - 2*ab;             e = sqrt(max(d2,0))
// Keep-first argmin via u64 (f32_bits<<32 | idx) min-reduction (valid: e >= 0,
// so bit order == value order, and min index wins on equal value bits).
//
// Workspace: 64 KB only (u16 gt0packed[16384] | u16 gt1[16384]).

#define SPN  2048
#define SPT  16384

__device__ __forceinline__ void sp_reproject(const float* __restrict__ T, int b,
                                             float x, float y,
                                             float& X, float& Y, float& S) {
  const float* H = T + b * 9;
  float p0 = __fadd_rn(__fadd_rn(__fmul_rn(H[0], x), __fmul_rn(H[1], y)), H[2]);
  float p1 = __fadd_rn(__fadd_rn(__fmul_rn(H[3], x), __fmul_rn(H[4], y)), H[5]);
  float p2 = __fadd_rn(__fadd_rn(__fmul_rn(H[6], x), __fmul_rn(H[7], y)), H[8]);
  float den = __fadd_rn(p2, 1e-8f);
  X = __fdiv_rn(p0, den);
  Y = __fdiv_rn(p1, den);
  S = __fadd_rn(__fmul_rn(X, X), __fmul_rn(Y, Y));
}

__global__ __launch_bounds__(256) void SuperPointMatchesGenerator_56925496541369_kernel(
    const float2* __restrict__ k0, const float2* __restrict__ k1,
    const float* __restrict__ T, unsigned short* __restrict__ gt0p,
    unsigned short* __restrict__ gt1, float* __restrict__ out_mind) {
  const bool mode1 = blockIdx.x >= (SPT / 8);             // block-uniform branch
  const int base = (mode1 ? blockIdx.x - SPT / 8 : blockIdx.x) * 8;
  const int b = base >> 11;
  const int cb = b << 11;

  float rx[8], ry[8], rs[8], bv[8];
  int bi[8];
#pragma unroll
  for (int r = 0; r < 8; r++) { bv[r] = INFINITY; bi[r] = 0; }

  if (!mode1) {
    // rows = reproject(kpts0[base..base+7]); candidates = kpts1
#pragma unroll
    for (int r = 0; r < 8; r++) {
      float2 p = k0[base + r];
      sp_reproject(T, b, p.x, p.y, rx[r], ry[r], rs[r]);   // rs = a2
    }
#pragma unroll 8
    for (int c = threadIdx.x; c < SPN; c += 256) {
      float2 p = k1[cb + c];
      float b2 = __fadd_rn(__fmul_rn(p.x, p.x), __fmul_rn(p.y, p.y));
#pragma unroll
      for (int r = 0; r < 8; r++) {
        float ab = __fadd_rn(__fmul_rn(rx[r], p.x), __fmul_rn(ry[r], p.y));
        float d2 = __fsub_rn(__fadd_rn(rs[r], b2), __fmul_rn(2.0f, ab));
        float e = __fsqrt_rn(fmaxf(d2, 0.0f));
        if (e < bv[r]) { bv[r] = e; bi[r] = c; }
      }
    }
  } else {
    // rows = kpts1[base..base+7]; candidates = reproject(kpts0)
#pragma unroll
    for (int r = 0; r < 8; r++) {
      float2 p = k1[base + r];
      rx[r] = p.x; ry[r] = p.y;
      rs[r] = __fadd_rn(__fmul_rn(p.x, p.x), __fmul_rn(p.y, p.y));  // b2
    }
#pragma unroll 4
    for (int c = threadIdx.x; c < SPN; c += 256) {
      float2 p = k0[cb + c];
      float cx, cy, a2;
      sp_reproject(T, b, p.x, p.y, cx, cy, a2);
#pragma unroll
      for (int r = 0; r < 8; r++) {
        float ab = __fadd_rn(__fmul_rn(rx[r], cx), __fmul_rn(ry[r], cy));
        float d2 = __fsub_rn(__fadd_rn(a2, rs[r]), __fmul_rn(2.0f, ab));
        float e = __fsqrt_rn(fmaxf(d2, 0.0f));
        if (e < bv[r]) { bv[r] = e; bi[r] = c; }
      }
    }
  }

  __shared__ unsigned long long part[4];
#pragma unroll
  for (int r = 0; r < 8; r++) {
    if (r) __syncthreads();
    unsigned long long key =
        ((unsigned long long)__float_as_uint(bv[r]) << 32) | (unsigned)bi[r];
#pragma unroll
    for (int off = 32; off > 0; off >>= 1) {
      unsigned long long o = __shfl_down(key, off);
      if (o < key) key = o;
    }
    if ((threadIdx.x & 63) == 0) part[threadIdx.x >> 6] = key;
    __syncthreads();
    if (threadIdx.x == 0) {
      unsigned long long k = part[0];
#pragma unroll
      for (int w = 1; w < 4; w++)
        if (part[w] < k) k = part[w];
      int idx = (int)(k & 0x7ffu);
      if (!mode1) {
        float e = __uint_as_float((unsigned)(k >> 32));
        unsigned short pk = (unsigned short)idx;
        if (e > 3.0f) pk |= 0x8000u;       // strict >, exact fp32
        gt0p[base + r] = pk;
        out_mind[base + r] = e;            // min_dist0, f32
      } else {
        gt1[base + r] = (unsigned short)idx;
      }
    }
  }
}

__global__ __launch_bounds__(256) void SuperPointMatchesGenerator_56925496541369_final(
    const unsigned short* __restrict__ gt0p, const unsigned short* __restrict__ gt1,
    float* __restrict__ out) {
  int t = blockIdx.x * 256 + threadIdx.x;
  if (t >= SPT) return;
  int b = t >> 11, i = t & 2047;
  int cb = b << 11;

  // gt_matches0[b, i]
  unsigned short p0 = gt0p[t];
  int m0 = p0 & 0x7ff;
  bool far0 = (p0 & 0x8000u) != 0;
  bool ok0 = (!far0) && ((int)gt1[cb + m0] == i);
  out[t] = ok0 ? (float)m0 : -1.0f;

  // gt_matches1[b, j] with j = i (pure gather; validity => injectivity)
  int istar = gt1[t];
  unsigned short ps = gt0p[cb + istar];
  bool ok1 = (((int)(ps & 0x7ff)) == i) && ((ps & 0x8000u) == 0);
  out[SPT + t] = ok1 ? (float)istar : -1.0f;
}

extern "C" void kernel_launch(void* const* d_in, const int* in_sizes, int n_in,
                              void* d_out, int out_size, void* d_ws, size_t ws_size,
                              hipStream_t stream) {
  (void)in_sizes; (void)n_in; (void)out_size; (void)ws_size;
  const float2* k0 = (const float2*)d_in[0];   // [8,2048,2] f32
  const float2* k1 = (const float2*)d_in[1];   // [8,2048,2] f32
  const float* T   = (const float*)d_in[2];    // [8,3,3]    f32
  float* out = (float*)d_out;                  // f32: 16384 | 16384 | 16384

  unsigned short* gt0p = (unsigned short*)d_ws;  // 32 KB
  unsigned short* gt1  = gt0p + SPT;             // 32 KB (total 64 KB)

  SuperPointMatchesGenerator_56925496541369_kernel<<<2 * (SPT / 8), 256, 0, stream>>>(
      k0, k1, T, gt0p, gt1, out + 2 * SPT);
  SuperPointMatchesGenerator_56925496541369_final<<<SPT / 256, 256, 0, stream>>>(
      gt0p, gt1, out);
}

// Round 6
// 84.085 us; speedup vs baseline: 1.2104x; 1.2104x over previous
//
#include <hip/hip_runtime.h>

// SuperPointMatchesGenerator: B=8, N0=N1=2048 mutual-NN under homography.
// d_out f32, concat: gt_matches0[8,2048] | gt_matches1[8,2048] | min_dist0[8,2048]
//
// R6 optimizations vs R5 (49.5us main kernel, VALU-bound, VALUBusy 78%):
//  1. argmin compares clamped d2 (monotone wrt sqrt); sqrt only for the 16K
//     winners in the epilogue. Removes 67M quarter-rate trans ops.
//  2. prep kernel precomputes reproject(kpts0)->(X,Y,a2) and kpts1->(x,y,b2)
//     as float4 in ws. Removes all __fdiv_rn chains from the hot loop
//     (R5 mode1 recomputed 4.2M reprojections; mode0 prologue 8/thread).
//  3. main-kernel modes are now symmetric (swap row/cand pointers); IEEE
//     add/mul commutativity keeps d2 bit-exact vs reference order.
//  4. epilogue: all 8 rows wave-reduced with ILP, ONE __syncthreads (R5 had 8).
//
// FP exactness vs numpy-f32 (no FMA contraction, explicit __f*_rn):
//   p_i = (H[i0]*x + H[i1]*y) + H[i2];  X = p0/(p2+1e-8);  a2 = X*X + Y*Y;
//   d2  = (a2 + b2) - 2*ab;  compare max(d2,0); winner e = sqrt(max(d2,0)).
// Keep-first argmin via u64 (f32_bits<<32 | idx) min (d2m >= 0 so bit order
// == value order; min index wins on equal value bits).
//
// ws layout (full path, 576KB): q0 f4[16384] | q1 f4[16384] | gt0p u16[16384] |
// gt1 u16[16384]. If ws_size is too small, falls back to the R5 kernels
// (deterministic branch on a constant -> same work every call).

#define SPN 2048
#define SPT 16384

__device__ __forceinline__ void sp_reproject(const float* __restrict__ T, int b,
                                             float x, float y,
                                             float& X, float& Y, float& S) {
  const float* H = T + b * 9;
  float p0 = __fadd_rn(__fadd_rn(__fmul_rn(H[0], x), __fmul_rn(H[1], y)), H[2]);
  float p1 = __fadd_rn(__fadd_rn(__fmul_rn(H[3], x), __fmul_rn(H[4], y)), H[5]);
  float p2 = __fadd_rn(__fadd_rn(__fmul_rn(H[6], x), __fmul_rn(H[7], y)), H[8]);
  float den = __fadd_rn(p2, 1e-8f);
  X = __fdiv_rn(p0, den);
  Y = __fdiv_rn(p1, den);
  S = __fadd_rn(__fmul_rn(X, X), __fmul_rn(Y, Y));
}

__global__ __launch_bounds__(256) void sp_prep(
    const float2* __restrict__ k0, const float2* __restrict__ k1,
    const float* __restrict__ T, float4* __restrict__ q0, float4* __restrict__ q1) {
  int t = blockIdx.x * 256 + threadIdx.x;
  if (t < SPT) {
    float2 p = k0[t];
    float X, Y, S;
    sp_reproject(T, t >> 11, p.x, p.y, X, Y, S);
    q0[t] = make_float4(X, Y, S, 0.0f);
  } else {
    int u = t - SPT;
    float2 p = k1[u];
    float S = __fadd_rn(__fmul_rn(p.x, p.x), __fmul_rn(p.y, p.y));
    q1[u] = make_float4(p.x, p.y, S, 0.0f);
  }
}

__global__ __launch_bounds__(256) void SuperPointMatchesGenerator_56925496541369_kernel(
    const float4* __restrict__ q0, const float4* __restrict__ q1,
    unsigned short* __restrict__ gt0p, unsigned short* __restrict__ gt1,
    float* __restrict__ out_mind) {
  const bool m1 = blockIdx.x >= SPN;              // block-uniform
  const int base = (m1 ? blockIdx.x - SPN : blockIdx.x) * 8;
  const int b = base >> 11, cb = b << 11;
  const float4* __restrict__ qr = m1 ? q1 : q0;   // rows
  const float4* __restrict__ qc = m1 ? q0 : q1;   // candidates

  float rx[8], ry[8], rs[8], bv[8];
  int bi[8];
#pragma unroll
  for (int r = 0; r < 8; r++) {
    float4 v = qr[base + r];                      // broadcast (uniform addr)
    rx[r] = v.x; ry[r] = v.y; rs[r] = v.z;
    bv[r] = INFINITY; bi[r] = 0;
  }

#pragma unroll 4
  for (int c = threadIdx.x; c < SPN; c += 256) {
    float4 v = qc[cb + c];
#pragma unroll
    for (int r = 0; r < 8; r++) {
      float ab = __fadd_rn(__fmul_rn(rx[r], v.x), __fmul_rn(ry[r], v.y));
      float d2 = __fsub_rn(__fadd_rn(rs[r], v.z), __fmul_rn(2.0f, ab));
      float dm = fmaxf(d2, 0.0f);                 // compare clamped d2, not sqrt
      if (dm < bv[r]) { bv[r] = dm; bi[r] = c; }
    }
  }

  unsigned long long key[8];
#pragma unroll
  for (int r = 0; r < 8; r++)
    key[r] = ((unsigned long long)__float_as_uint(bv[r]) << 32) | (unsigned)bi[r];
#pragma unroll
  for (int off = 32; off > 0; off >>= 1) {
#pragma unroll
    for (int r = 0; r < 8; r++) {
      unsigned long long o = __shfl_down(key[r], off);
      if (o < key[r]) key[r] = o;
    }
  }
  __shared__ unsigned long long part[4][8];
  if ((threadIdx.x & 63) == 0) {
    int w = threadIdx.x >> 6;
#pragma unroll
    for (int r = 0; r < 8; r++) part[w][r] = key[r];
  }
  __syncthreads();                                 // single barrier
  if (threadIdx.x < 8) {
    int r = threadIdx.x;
    unsigned long long k = part[0][r];
#pragma unroll
    for (int w = 1; w < 4; w++)
      if (part[w][r] < k) k = part[w][r];
    int idx = (int)(k & 0x7ffu);
    if (!m1) {
      float dm = __uint_as_float((unsigned)(k >> 32));
      float e = __fsqrt_rn(dm);                    // sqrt only for winners
      unsigned short pk = (unsigned short)idx;
      if (e > 3.0f) pk |= 0x8000u;                 // strict >, exact fp32
      gt0p[base + r] = pk;
      out_mind[base + r] = e;
    } else {
      gt1[base + r] = (unsigned short)idx;
    }
  }
}

__global__ __launch_bounds__(256) void SuperPointMatchesGenerator_56925496541369_final(
    const unsigned short* __restrict__ gt0p, const unsigned short* __restrict__ gt1,
    float* __restrict__ out) {
  int t = blockIdx.x * 256 + threadIdx.x;
  if (t >= SPT) return;
  int b = t >> 11, i = t & 2047, cb = b << 11;

  unsigned short p0 = gt0p[t];
  int m0 = p0 & 0x7ff;
  bool ok0 = ((p0 & 0x8000u) == 0) && ((int)gt1[cb + m0] == i);
  out[t] = ok0 ? (float)m0 : -1.0f;

  int istar = gt1[t];                              // gather form of the scatter
  unsigned short ps = gt0p[cb + istar];
  bool ok1 = (((int)(ps & 0x7ff)) == i) && ((ps & 0x8000u) == 0);
  out[SPT + t] = ok1 ? (float)istar : -1.0f;
}

// ---------- R5 fallback (proven-correct) for small ws_size ----------
__global__ __launch_bounds__(256) void sp_fallback_main(
    const float2* __restrict__ k0, const float2* __restrict__ k1,
    const float* __restrict__ T, unsigned short* __restrict__ gt0p,
    unsigned short* __restrict__ gt1, float* __restrict__ out_mind) {
  const bool mode1 = blockIdx.x >= SPN;
  const int base = (mode1 ? blockIdx.x - SPN : blockIdx.x) * 8;
  const int b = base >> 11, cb = b << 11;
  float rx[8], ry[8], rs[8], bv[8];
  int bi[8];
#pragma unroll
  for (int r = 0; r < 8; r++) { bv[r] = INFINITY; bi[r] = 0; }
  if (!mode1) {
#pragma unroll
    for (int r = 0; r < 8; r++) {
      float2 p = k0[base + r];
      sp_reproject(T, b, p.x, p.y, rx[r], ry[r], rs[r]);
    }
    for (int c = threadIdx.x; c < SPN; c += 256) {
      float2 p = k1[cb + c];
      float b2 = __fadd_rn(__fmul_rn(p.x, p.x), __fmul_rn(p.y, p.y));
#pragma unroll
      for (int r = 0; r < 8; r++) {
        float ab = __fadd_rn(__fmul_rn(rx[r], p.x), __fmul_rn(ry[r], p.y));
        float d2 = __fsub_rn(__fadd_rn(rs[r], b2), __fmul_rn(2.0f, ab));
        float dm = fmaxf(d2, 0.0f);
        if (dm < bv[r]) { bv[r] = dm; bi[r] = c; }
      }
    }
  } else {
#pragma unroll
    for (int r = 0; r < 8; r++) {
      float2 p = k1[base + r];
      rx[r] = p.x; ry[r] = p.y;
      rs[r] = __fadd_rn(__fmul_rn(p.x, p.x), __fmul_rn(p.y, p.y));
    }
    for (int c = threadIdx.x; c < SPN; c += 256) {
      float2 p = k0[cb + c];
      float cx, cy, a2;
      sp_reproject(T, b, p.x, p.y, cx, cy, a2);
#pragma unroll
      for (int r = 0; r < 8; r++) {
        float ab = __fadd_rn(__fmul_rn(rx[r], cx), __fmul_rn(ry[r], cy));
        float d2 = __fsub_rn(__fadd_rn(a2, rs[r]), __fmul_rn(2.0f, ab));
        float dm = fmaxf(d2, 0.0f);
        if (dm < bv[r]) { bv[r] = dm; bi[r] = c; }
      }
    }
  }
  unsigned long long key[8];
#pragma unroll
  for (int r = 0; r < 8; r++)
    key[r] = ((unsigned long long)__float_as_uint(bv[r]) << 32) | (unsigned)bi[r];
#pragma unroll
  for (int off = 32; off > 0; off >>= 1) {
#pragma unroll
    for (int r = 0; r < 8; r++) {
      unsigned long long o = __shfl_down(key[r], off);
      if (o < key[r]) key[r] = o;
    }
  }
  __shared__ unsigned long long part[4][8];
  if ((threadIdx.x & 63) == 0) {
    int w = threadIdx.x >> 6;
#pragma unroll
    for (int r = 0; r < 8; r++) part[w][r] = key[r];
  }
  __syncthreads();
  if (threadIdx.x < 8) {
    int r = threadIdx.x;
    unsigned long long k = part[0][r];
#pragma unroll
    for (int w = 1; w < 4; w++)
      if (part[w][r] < k) k = part[w][r];
    int idx = (int)(k & 0x7ffu);
    if (!mode1) {
      float e = __fsqrt_rn(__uint_as_float((unsigned)(k >> 32)));
      unsigned short pk = (unsigned short)idx;
      if (e > 3.0f) pk |= 0x8000u;
      gt0p[base + r] = pk;
      out_mind[base + r] = e;
    } else {
      gt1[base + r] = (unsigned short)idx;
    }
  }
}

extern "C" void kernel_launch(void* const* d_in, const int* in_sizes, int n_in,
                              void* d_out, int out_size, void* d_ws, size_t ws_size,
                              hipStream_t stream) {
  (void)in_sizes; (void)n_in; (void)out_size;
  const float2* k0 = (const float2*)d_in[0];
  const float2* k1 = (const float2*)d_in[1];
  const float* T   = (const float*)d_in[2];
  float* out = (float*)d_out;

  const size_t need = (size_t)2 * SPT * sizeof(float4) + (size_t)2 * SPT * sizeof(unsigned short);
  if (ws_size >= need) {
    float4* q0 = (float4*)d_ws;                       // 256 KB
    float4* q1 = q0 + SPT;                            // 256 KB
    unsigned short* gt0p = (unsigned short*)(q1 + SPT);  // 32 KB
    unsigned short* gt1  = gt0p + SPT;                   // 32 KB
    sp_prep<<<2 * SPT / 256, 256, 0, stream>>>(k0, k1, T, q0, q1);
    SuperPointMatchesGenerator_56925496541369_kernel<<<2 * SPN, 256, 0, stream>>>(
        q0, q1, gt0p, gt1, out + 2 * SPT);
    SuperPointMatchesGenerator_56925496541369_final<<<SPT / 256, 256, 0, stream>>>(
        gt0p, gt1, out);
  } else {
    unsigned short* gt0p = (unsigned short*)d_ws;
    unsigned short* gt1  = gt0p + SPT;
    sp_fallback_main<<<2 * SPN, 256, 0, stream>>>(k0, k1, T, gt0p, gt1, out + 2 * SPT);
    SuperPointMatchesGenerator_56925496541369_final<<<SPT / 256, 256, 0, stream>>>(
        gt0p, gt1, out);
  }
}